// Round 1
// baseline (57.369 us; speedup 1.0000x reference)
//
#include <hip/hip_runtime.h>

#define WAVES_PER_BLOCK 4
#define NACC 256   // striped double accumulators in d_ws (2 KB)

__global__ void dlr_init(double* __restrict__ acc) {
    acc[threadIdx.x] = 0.0;
}

__global__ __launch_bounds__(256) void dlr_main(const float* __restrict__ x,
                                                const int* __restrict__ target,
                                                double* __restrict__ acc,
                                                int B, int C) {
    const int lane = threadIdx.x & 63;
    const int wave = threadIdx.x >> 6;
    const int row  = blockIdx.x * WAVES_PER_BLOCK + wave;

    float loss = 0.0f;
    if (row < B) {
        const int t = target[row];
        const float* rp = x + (size_t)row * (size_t)C;
        const float4* rp4 = reinterpret_cast<const float4*>(rp);
        const int n4 = C >> 2;

        const float NEG = -__builtin_inff();
        float v1 = NEG, v2 = NEG, v3 = NEG;
        int   i1 = 0x7fffffff;
        float xy = NEG;

        // streaming scan: per-lane top-3 (branchless insert), argmax index, x[target]
        for (int i = lane; i < n4; i += 64) {
            float4 q = rp4[i];
            const int c = i << 2;
            float vv[4] = {q.x, q.y, q.z, q.w};
            #pragma unroll
            for (int j = 0; j < 4; ++j) {
                float v = vv[j];
                int idx = c + j;
                float nv3 = (v > v2) ? v2 : ((v > v3) ? v : v3);
                float nv2 = (v > v1) ? v1 : ((v > v2) ? v : v2);
                bool  g1  = (v > v1);           // strict > keeps smaller index on ties
                v3 = nv3; v2 = nv2;
                if (g1) { v1 = v; i1 = idx; }
                if (idx == t) xy = v;
            }
        }
        // tail if C % 4 != 0 (no-op for C=1000)
        for (int c = (n4 << 2) + lane; c < C; c += 64) {
            float v = rp[c];
            float nv3 = (v > v2) ? v2 : ((v > v3) ? v : v3);
            float nv2 = (v > v1) ? v1 : ((v > v2) ? v : v2);
            bool  g1  = (v > v1);
            v3 = nv3; v2 = nv2;
            if (g1) { v1 = v; i1 = c; }
            if (c == t) xy = v;
        }

        // 64-lane butterfly merge of sorted triples
        #pragma unroll
        for (int off = 1; off < 64; off <<= 1) {
            float b1 = __shfl_xor(v1, off, 64);
            int   bi = __shfl_xor(i1, off, 64);
            float b2 = __shfl_xor(v2, off, 64);
            float b3 = __shfl_xor(v3, off, 64);
            float bx = __shfl_xor(xy, off, 64);
            // insert (b1, bi)
            if (b1 > v1)      { v3 = v2; v2 = v1; v1 = b1; i1 = bi; }
            else {
                if (b1 == v1 && bi < i1) i1 = bi;   // jax top_k: smaller index wins ties
                if (b1 > v2)  { v3 = v2; v2 = b1; }
                else if (b1 > v3) v3 = b1;
            }
            // insert b2 (b2 <= b1 <= v1, so only challenges v2/v3)
            if (b2 > v2)      { v3 = v2; v2 = b2; }
            else if (b2 > v3) v3 = b2;
            // insert b3
            if (b3 > v3) v3 = b3;
            xy = fmaxf(xy, bx);
        }

        const float ind = (i1 == t) ? 1.0f : 0.0f;
        const float num = -(xy - v2 * ind - v1 * (1.0f - ind));
        loss = num / (v1 - v3 + 1e-12f);
    }

    __shared__ float s[WAVES_PER_BLOCK];
    if (lane == 0) s[wave] = loss;
    __syncthreads();
    if (threadIdx.x == 0) {
        double bs = 0.0;
        #pragma unroll
        for (int w = 0; w < WAVES_PER_BLOCK; ++w) bs += (double)s[w];
        atomicAdd(&acc[blockIdx.x & (NACC - 1)], bs);
    }
}

__global__ void dlr_finalize(const double* __restrict__ acc,
                             float* __restrict__ out, int B) {
    const int lane = threadIdx.x;   // 64 threads
    double s = 0.0;
    for (int i = lane; i < NACC; i += 64) s += acc[i];
    #pragma unroll
    for (int off = 32; off > 0; off >>= 1)
        s += __shfl_xor(s, off, 64);
    if (lane == 0) out[0] = (float)(s / (double)B);
}

extern "C" void kernel_launch(void* const* d_in, const int* in_sizes, int n_in,
                              void* d_out, int out_size, void* d_ws, size_t ws_size,
                              hipStream_t stream) {
    const float* x   = (const float*)d_in[0];
    const int*   tgt = (const int*)d_in[1];
    const int B = in_sizes[1];
    const int C = in_sizes[0] / B;

    double* acc = (double*)d_ws;   // needs NACC*8 = 2 KB of scratch

    dlr_init<<<1, NACC, 0, stream>>>(acc);
    const int grid = (B + WAVES_PER_BLOCK - 1) / WAVES_PER_BLOCK;
    dlr_main<<<grid, 64 * WAVES_PER_BLOCK, 0, stream>>>(x, tgt, acc, B, C);
    dlr_finalize<<<1, 64, 0, stream>>>(acc, (float*)d_out, B);
}

// Round 2
// 48.351 us; speedup vs baseline: 1.1865x; 1.1865x over previous
//
#include <hip/hip_runtime.h>

#define NBLK 2048
#define TPB  256
// 16 lanes per row-group; 4 groups/wave; 4 waves/block -> 32768 groups total.
// B=65536 -> exactly 2 rows per group. Persistent grid: 2048 blocks = 8/CU.

__global__ __launch_bounds__(TPB, 8) void dlr_main(const float* __restrict__ x,
                                                   const int* __restrict__ target,
                                                   double* __restrict__ bsum,
                                                   int B, int C) {
    const int tid  = threadIdx.x;
    const int lane = tid & 63;
    const int l16  = lane & 15;
    const int wid  = (blockIdx.x << 2) + (tid >> 6);
    const int group0  = (wid << 2) + (lane >> 4);
    const int ngroups = NBLK * 16;
    const int n4 = C >> 2;
    const float NEG = -__builtin_inff();

    double lsum = 0.0;

    for (int row = group0; row < B; row += ngroups) {
        const int t = target[row];
        const float* rp = x + (size_t)row * (size_t)C;
        const float4* rp4 = reinterpret_cast<const float4*>(rp);
        const float xy = rp[t];   // same addr across the 16-lane group -> broadcast

        float v1 = NEG, v2 = NEG, v3 = NEG;
        int   im = 0x7fffffff;

        // scan: chunks of 64 float4 (16 lanes x 4 in flight), med3 top-3 insert
        for (int ib = 0; ib < n4; ib += 64) {
            float4 q[4];
            int    c0[4];
            #pragma unroll
            for (int u = 0; u < 4; ++u) {
                const int i = ib + l16 + (u << 4);
                c0[u] = i << 2;
                if (i < n4) q[u] = rp4[i];
                else { q[u].x = NEG; q[u].y = NEG; q[u].z = NEG; q[u].w = NEG; }
            }
            #pragma unroll
            for (int u = 0; u < 4; ++u) {
                const float vv[4] = {q[u].x, q[u].y, q[u].z, q[u].w};
                #pragma unroll
                for (int j = 0; j < 4; ++j) {
                    const float v = vv[j];
                    const float nv1 = fmaxf(v1, v);
                    const float nv2 = __builtin_amdgcn_fmed3f(v, v1, v2);
                    const float nv3 = __builtin_amdgcn_fmed3f(v, v2, v3);
                    if (v > v1) im = c0[u] + j;   // strict >: smallest index wins ties
                    v1 = nv1; v2 = nv2; v3 = nv3;
                }
            }
        }
        // tail if C % 4 != 0 (no-op for C=1000)
        for (int c = (n4 << 2) + l16; c < C; c += 16) {
            const float v = rp[c];
            const float nv1 = fmaxf(v1, v);
            const float nv2 = __builtin_amdgcn_fmed3f(v, v1, v2);
            const float nv3 = __builtin_amdgcn_fmed3f(v, v2, v3);
            if (v > v1) im = c;
            v1 = nv1; v2 = nv2; v3 = nv3;
        }

        // 4-step butterfly merge within the 16-lane group
        #pragma unroll
        for (int off = 1; off < 16; off <<= 1) {
            const float b1 = __shfl_xor(v1, off, 64);
            const float b2 = __shfl_xor(v2, off, 64);
            const float b3 = __shfl_xor(v3, off, 64);
            const int   bi = __shfl_xor(im, off, 64);
            const bool bg = (b1 > v1) || (b1 == v1 && bi < im); // jax tie: min index
            if (bg) im = bi;
            // insert b1
            const float t1 = fmaxf(v1, b1);
            const float t2 = __builtin_amdgcn_fmed3f(b1, v1, v2);
            const float t3 = __builtin_amdgcn_fmed3f(b1, v2, v3);
            // insert b2 (b2 <= b1 <= t1)
            const float u2 = fmaxf(t2, b2);
            const float u3 = __builtin_amdgcn_fmed3f(b2, t2, t3);
            // insert b3 (b3 <= b2 <= u2)
            v1 = t1; v2 = u2; v3 = fmaxf(u3, b3);
        }

        const float ind = (im == t) ? 1.0f : 0.0f;
        const float num = -(xy - v2 * ind - v1 * (1.0f - ind));
        lsum += (double)(num / (v1 - v3 + 1e-12f));
    }

    // block reduction: one leader per 16-lane group -> 16 doubles in LDS
    __shared__ double s[TPB / 16];
    if (l16 == 0) s[tid >> 4] = lsum;
    __syncthreads();
    if (tid == 0) {
        double b = 0.0;
        #pragma unroll
        for (int i = 0; i < TPB / 16; ++i) b += s[i];
        bsum[blockIdx.x] = b;
    }
}

__global__ void dlr_finalize(const double* __restrict__ bsum,
                             float* __restrict__ out, int B, int n) {
    const int tid = threadIdx.x;   // 256 threads
    double sum = 0.0;
    for (int i = tid; i < n; i += 256) sum += bsum[i];
    #pragma unroll
    for (int off = 32; off > 0; off >>= 1)
        sum += __shfl_xor(sum, off, 64);
    __shared__ double w[4];
    if ((tid & 63) == 0) w[tid >> 6] = sum;
    __syncthreads();
    if (tid == 0)
        out[0] = (float)((w[0] + w[1] + w[2] + w[3]) / (double)B);
}

extern "C" void kernel_launch(void* const* d_in, const int* in_sizes, int n_in,
                              void* d_out, int out_size, void* d_ws, size_t ws_size,
                              hipStream_t stream) {
    const float* x   = (const float*)d_in[0];
    const int*   tgt = (const int*)d_in[1];
    const int B = in_sizes[1];
    const int C = in_sizes[0] / B;

    double* bsum = (double*)d_ws;   // NBLK * 8 = 16 KB scratch

    dlr_main<<<NBLK, TPB, 0, stream>>>(x, tgt, bsum, B, C);
    dlr_finalize<<<1, 256, 0, stream>>>(bsum, (float*)d_out, B, NBLK);
}